// Round 8
// baseline (217.256 us; speedup 1.0000x reference)
//
#include <hip/hip_runtime.h>

#define NN 16384   // total nodes (4*64*64)
#define CC 48      // channels

typedef __attribute__((ext_vector_type(8))) short bf16x8;
typedef __attribute__((ext_vector_type(4))) float f32x4;

__device__ __forceinline__ unsigned short f2bf(float f) {
  unsigned u = __float_as_uint(f);
  unsigned r = ((u >> 16) & 1u) + 0x7fffu;   // RNE
  return (unsigned short)((u + r) >> 16);
}
__device__ __forceinline__ float bf2f(unsigned short h) {
  return __uint_as_float(((unsigned)h) << 16);
}

// Parallel sorted-insert of key c into ascending q[0..8] (verified R0 form).
// Inserting c >= q[8] is a provable NO-OP (all mins return q[k], all maxes
// return q[k]) — relied on by the wave-uniform gate below.
__device__ __forceinline__ void ins9(double c, double q[9]) {
  double m1 = fmin(q[1], c), m2 = fmin(q[2], c), m3 = fmin(q[3], c),
         m4 = fmin(q[4], c), m5 = fmin(q[5], c), m6 = fmin(q[6], c),
         m7 = fmin(q[7], c), m8 = fmin(q[8], c);
  double n0 = fmin(q[0], c);
  double n1 = fmax(q[0], m1), n2 = fmax(q[1], m2), n3 = fmax(q[2], m3),
         n4 = fmax(q[3], m4), n5 = fmax(q[4], m5), n6 = fmax(q[5], m6),
         n7 = fmax(q[6], m7), n8 = fmax(q[7], m8);
  q[0] = n0; q[1] = n1; q[2] = n2; q[3] = n3; q[4] = n4;
  q[5] = n5; q[6] = n6; q[7] = n7; q[8] = n8;
}

// ---------- kernel 1: [B,C,H,W] -> xg[N][52] fp32, xh/xl[N][64] bf16 split, sqv[N] ----------
// Verified R7 version (float4 loads, ushort4 stores). Unchanged.
__global__ __launch_bounds__(256) void prep_kernel(const float* __restrict__ x,
                                                   float* __restrict__ xg,
                                                   unsigned short* __restrict__ xh,
                                                   unsigned short* __restrict__ xl,
                                                   float* __restrict__ sqv,
                                                   int* __restrict__ deg) {
  __shared__ float tile[48][68];   // pad 68: float4-aligned rows (272 B)
  __shared__ float sqcol[64];
  int tid = threadIdx.x;
  int b   = blockIdx.x >> 6;          // batch image 0..3
  int hw0 = (blockIdx.x & 63) << 6;   // 64-wide hw tile
  if (tid < 64) deg[blockIdx.x * 64 + tid] = 0;
  const float4* x4 = (const float4*)x;
#pragma unroll
  for (int p = 0; p < 3; ++p) {
    int it = tid + p * 256;           // 768 float4 = 48 rows x 16
    int r = it >> 4, c4 = it & 15;
    float4 v = x4[(b * 48 + r) * 1024 + (hw0 >> 2) + c4];
    *(float4*)&tile[r][c4 * 4] = v;
  }
  __syncthreads();
  if (tid < 64) {
    float s = 0.f;
#pragma unroll
    for (int r = 0; r < 48; ++r) { float v = tile[r][tid]; s += v * v; }
    sqcol[tid] = s;
    int node = b * 4096 + hw0 + tid;
    sqv[node] = (node == NN - 1) ? __builtin_inff() : s;
  }
  __syncthreads();
  float4* xg4 = (float4*)xg;
#pragma unroll
  for (int p = 0; p < 4; ++p) {
    int it = tid + p * 256;
    if (it < 832) {
      int col = it / 13;
      int q   = it - col * 13;
      float4 v;
      if (q < 12) {
        v.x = tile[q * 4 + 0][col]; v.y = tile[q * 4 + 1][col];
        v.z = tile[q * 4 + 2][col]; v.w = tile[q * 4 + 3][col];
      } else {
        v.x = sqcol[col]; v.y = 0.f; v.z = 0.f; v.w = 0.f;
      }
      xg4[(b * 4096 + hw0 + col) * 13 + q] = v;
    }
  }
  // bf16 hi/lo split, channels padded 48..63 with zeros; ushort4 stores
#pragma unroll
  for (int p = 0; p < 4; ++p) {
    int it = tid + p * 256;          // 1024 = 64 nodes x 16 ch-quads
    int col = it >> 4, cq = it & 15, ch = cq * 4;
    ushort4 h4, l4;
    if (ch < 48) {
      float v0 = tile[ch + 0][col], v1 = tile[ch + 1][col],
            v2 = tile[ch + 2][col], v3 = tile[ch + 3][col];
      h4.x = f2bf(v0); h4.y = f2bf(v1); h4.z = f2bf(v2); h4.w = f2bf(v3);
      l4.x = f2bf(v0 - bf2f(h4.x)); l4.y = f2bf(v1 - bf2f(h4.y));
      l4.z = f2bf(v2 - bf2f(h4.z)); l4.w = f2bf(v3 - bf2f(h4.w));
    } else {
      h4.x = h4.y = h4.z = h4.w = 0;
      l4.x = l4.y = l4.z = l4.w = 0;
    }
    size_t o = (size_t)(b * 4096 + hw0 + col) * 64 + ch;
    *(ushort4*)(xh + o) = h4;
    *(ushort4*)(xl + o) = l4;
  }
}

// ---------- kernel 2: MFMA distance + GATED exact f64 top-9, fused final merge ----------
// R6 structure verbatim (148.5us, verified). ONE change: the insert block is
// gated by a wave-uniform threshold test. Insert is needed iff
// key_new < q9[8]; ordinals are strictly increasing in-stream, so for equal
// k32 the candidate always loses => condition reduces to k32 < thr where
// thr = trunc(q9[8] * 2^-8) (exact; fmin clamp makes q9[8]=inf -> 0xFFFFFFFF,
// so the first 9 inserts always pass). Lanes with k32 >= thr inside a taken
// block run ins9 as a no-op (c >= q[8]); thr recompute is idempotent.
// Expected-order stats: P(any of 64 lanes inserts) ~ 1-(1-9/n)^64, mean
// taken-rate ~0.6-0.7 => ~30-40% of the 68-f64-op blocks (272 issue-cyc at
// half-rate DP) are skipped. Semantics bit-identical to R6.
__global__ __launch_bounds__(256, 4) void knn_kernel(const unsigned short* __restrict__ xh,
                                                     const unsigned short* __restrict__ xl,
                                                     const float* __restrict__ sqv,
                                                     int* __restrict__ nbr,
                                                     int* __restrict__ deg) {
  __shared__ unsigned long long fin[4][64][9];   // 18.4 KB, merge staging only
  int tid = threadIdx.x, wv = tid >> 6, lane = tid & 63;
  int qt = blockIdx.x;
  int col = lane & 15, quad = lane >> 4;
  int batch = qt >> 8;
  int cbase = batch * 4096 + wv * 1024;   // this wave's candidate quarter

  // resident B-frags (queries)
  int qnode = qt * 16 + col;
  bf16x8 bh0 = *(const bf16x8*)(xh + (size_t)qnode * 64 + quad * 8);
  bf16x8 bh1 = *(const bf16x8*)(xh + (size_t)qnode * 64 + 32 + quad * 8);
  bf16x8 bl0 = *(const bf16x8*)(xl + (size_t)qnode * 64 + quad * 8);
  bf16x8 bl1 = *(const bf16x8*)(xl + (size_t)qnode * 64 + 32 + quad * 8);

  double q9[9];
#pragma unroll
  for (int k = 0; k < 9; ++k) q9[k] = __builtin_inf();
  unsigned thr = 0xFFFFFFFFu;   // distance bits of current 9th-best

  // prefetch tile 0: A-frags (candidate node cbase + col) + sq float4
  const unsigned short* pah = xh + ((size_t)(cbase + col) * 64 + quad * 8);
  const unsigned short* pal = xl + ((size_t)(cbase + col) * 64 + quad * 8);
  const float*          psq = sqv + (cbase + quad * 4);
  bf16x8 nh0 = *(const bf16x8*)(pah);
  bf16x8 nh1 = *(const bf16x8*)(pah + 32);
  bf16x8 nl0 = *(const bf16x8*)(pal);
  bf16x8 nl1 = *(const bf16x8*)(pal + 32);
  float4 nsq = *(const float4*)(psq);

  double od = 0.0;   // ordinal base = t*4 (exact integer in f64)
  for (int t = 0; t < 64; ++t) {
    bf16x8 ch0 = nh0, ch1 = nh1, cl0 = nl0, cl1 = nl1;
    float4 csq = nsq;
    int adv = (t < 63) ? 1024 : 0;       // 16 nodes * 64 ch
    pah += adv; pal += adv;
    nh0 = *(const bf16x8*)(pah);
    nh1 = *(const bf16x8*)(pah + 32);
    nl0 = *(const bf16x8*)(pal);
    nl1 = *(const bf16x8*)(pal + 32);
    psq += (t < 63) ? 16 : 0;
    nsq = *(const float4*)(psq);

    f32x4 acc = {0.f, 0.f, 0.f, 0.f};
    acc = __builtin_amdgcn_mfma_f32_16x16x32_bf16(ch0, bh0, acc, 0, 0, 0);  // hi.hi k0-31
    acc = __builtin_amdgcn_mfma_f32_16x16x32_bf16(ch1, bh1, acc, 0, 0, 0);  // hi.hi k32-63
    acc = __builtin_amdgcn_mfma_f32_16x16x32_bf16(ch0, bl0, acc, 0, 0, 0);  // hi.lo
    acc = __builtin_amdgcn_mfma_f32_16x16x32_bf16(ch1, bl1, acc, 0, 0, 0);
    acc = __builtin_amdgcn_mfma_f32_16x16x32_bf16(cl0, bh0, acc, 0, 0, 0);  // lo.hi
    acc = __builtin_amdgcn_mfma_f32_16x16x32_bf16(cl1, bh1, acc, 0, 0, 0);

    float sq4[4] = {csq.x, csq.y, csq.z, csq.w};
#pragma unroll
    for (int reg = 0; reg < 4; ++reg) {
      float d = fmaf(-2.f, acc[reg], sq4[reg]);   // key: sq_j - 2 dot (sq_i dropped)
      unsigned k32 = __float_as_uint(d);
      k32 = ((int)k32 >= 0) ? (k32 | 0x80000000u) : ~k32;   // sortable map
      if (__any(k32 < thr)) {
        double key = fma((double)k32, 256.0, od + (double)reg);  // exact 40-bit int
        ins9(key, q9);
        thr = (unsigned)fmin(q9[8] * 0.00390625, 4294967295.0); // trunc, inf-safe
      }
    }
    od += 4.0;
  }

  // f64 keys -> exact (k32, o) -> j -> packed u64; stage for in-wave quad merge
  unsigned long long q9u[9];
#pragma unroll
  for (int k = 0; k < 9; ++k) {
    double d  = q9[k];
    double hi = floor(d * 0.00390625);     // d * 2^-8, exact
    double lo = d - hi * 256.0;            // ordinal o, exact
    unsigned k32 = (unsigned)hi;
    int o = (int)lo;
    int j = cbase + (o >> 2) * 16 + quad * 4 + (o & 3);
    q9u[k] = ((unsigned long long)k32 << 14) | (unsigned)j;
    fin[wv][lane][k] = q9u[k];
  }
  __threadfence_block();
  if (lane < 16) {
    // stage 1: merge the wave's 4 quads -> per-wave list for query col=lane
#pragma unroll
    for (int qd = 1; qd < 4; ++qd) {
      const unsigned long long* ob = fin[wv][qd * 16 + lane];
      for (int k = 0; k < 9; ++k) {
        unsigned long long key = ob[k];
        if (key >= q9u[8]) break;          // sorted ascending
        unsigned long long cu = key;
#pragma unroll
        for (int kk = 0; kk < 9; ++kk) {
          bool lt = cu < q9u[kk];
          unsigned long long mn = lt ? cu : q9u[kk];
          cu      = lt ? q9u[kk] : cu;
          q9u[kk] = mn;
        }
      }
    }
    // restage per-wave merged list (only fin[wv][0..15] touched; own quad
    // reads above covered 16..63, other waves never read fin[wv])
#pragma unroll
    for (int k = 0; k < 9; ++k) fin[wv][lane][k] = q9u[k];
  }
  __syncthreads();
  // stage 2: wave 0 merges the 4 per-wave lists -> FINAL top-9; write nbr/deg
  if (wv == 0 && lane < 16) {
#pragma unroll
    for (int ow = 1; ow < 4; ++ow) {
      const unsigned long long* ob = fin[ow][lane];
      for (int k = 0; k < 9; ++k) {
        unsigned long long key = ob[k];
        if (key >= q9u[8]) break;          // sorted ascending
        unsigned long long cu = key;
#pragma unroll
        for (int kk = 0; kk < 9; ++kk) {
          bool lt = cu < q9u[kk];
          unsigned long long mn = lt ? cu : q9u[kk];
          cu      = lt ? q9u[kk] : cu;
          q9u[kk] = mn;
        }
      }
    }
    int i = qt * 16 + lane;
    int outi[9];
#pragma unroll
    for (int k = 0; k < 9; ++k) outi[k] = (int)(q9u[k] & 0x3FFFull);
    // node 16383 sits alone in "batch 4": top_k over one valid entry + (-inf)
    // ties -> neighbors {16383, 0,1,...,7} (lowest-index tie-break).
    if (i == NN - 1) {
      outi[0] = NN - 1;
#pragma unroll
      for (int k = 1; k < 9; ++k) outi[k] = k - 1;
    }
#pragma unroll
    for (int k = 0; k < 9; ++k) {
      nbr[i * 9 + k] = outi[k];
      atomicAdd(&deg[outi[k]], 1);
    }
  }
}

// ---------- kernel 3: tx1 gather + out = relu(xf@W0 + tx1@W1 + b) ----------
// Verified R7 version (1024 blocks x 16 rows, 4 blocks/CU). Unchanged.
__global__ __launch_bounds__(256) void out_kernel(const float* __restrict__ xg,
                                                  const int* __restrict__ nbr,
                                                  const int* __restrict__ deg,
                                                  const float* __restrict__ W0,
                                                  const float* __restrict__ W1,
                                                  const float* __restrict__ bias,
                                                  float* __restrict__ out) {
  __shared__ float w0s[48 * 48], w1s[48 * 48], bsh[48];
  __shared__ __align__(16) float xr[16 * 48];
  __shared__ float tx[16 * 48];
  __shared__ float wd[16][9];
  __shared__ int   jn[16][9];
  __shared__ float din[16];
  int tid = threadIdx.x;
  int r0  = blockIdx.x * 16;

  // weight staging, vectorized: 2304 floats = 576 float4 per matrix
  const float4* W04 = (const float4*)W0;
  const float4* W14 = (const float4*)W1;
  float4* w0s4 = (float4*)w0s;
  float4* w1s4 = (float4*)w1s;
  for (int p = tid; p < 576; p += 256) { w0s4[p] = W04[p]; w1s4[p] = W14[p]; }
  if (tid < 48) bsh[tid] = bias[tid];
  if (tid < 16) {
    int d = deg[r0 + tid];
    din[tid] = d > 0 ? rsqrtf((float)d) : 0.0f;
  }
  const float4* xg4 = (const float4*)xg;
  float4* xr4 = (float4*)xr;
  if (tid < 192) {                      // 16 rows x 12 float4
    int r = tid / 12, q = tid - r * 12;
    xr4[r * 12 + q] = xg4[(r0 + r) * 13 + q];
  }
  if (tid < 144) {                      // 16 rows x 9 neighbors
    int r = tid / 9, k = tid - r * 9;
    int j = nbr[(r0 + r) * 9 + k];
    jn[r][k] = j;
    int d = deg[j];
    wd[r][k] = d > 0 ? rsqrtf((float)d) : 0.0f;
  }
  __syncthreads();

  for (int p = tid; p < 768; p += 256) {   // 16 rows x 48 ch
    int r = p / 48, ch = p - r * 48;
    float s = 0.f;
#pragma unroll
    for (int k = 0; k < 9; ++k) s += wd[r][k] * xg[jn[r][k] * 52 + ch];
    tx[r * 48 + ch] = -din[r] * s;
  }
  __syncthreads();

  for (int p = tid; p < 768; p += 256) {   // 16 rows x 48 outs
    int r = p / 48, o = p - r * 48;
    float acc = bsh[o];
#pragma unroll
    for (int cc = 0; cc < 48; ++cc)
      acc += xr[r * 48 + cc] * w0s[cc * 48 + o] + tx[r * 48 + cc] * w1s[cc * 48 + o];
    out[(r0 + r) * 48 + o] = fmaxf(acc, 0.f);
  }
}

extern "C" void kernel_launch(void* const* d_in, const int* in_sizes, int n_in,
                              void* d_out, int out_size, void* d_ws, size_t ws_size,
                              hipStream_t stream) {
  const float* x  = (const float*)d_in[0];
  const float* W0 = (const float*)d_in[1];
  const float* W1 = (const float*)d_in[2];
  const float* b  = (const float*)d_in[3];
  float* out = (float*)d_out;
  char* ws = (char*)d_ws;
  float*          xg   = (float*)(ws);                       // 3,407,872 B
  unsigned short* xh   = (unsigned short*)(ws + 3407872);    // 2,097,152 B
  unsigned short* xl   = (unsigned short*)(ws + 5505024);    // 2,097,152 B
  float*          sqv  = (float*)(ws + 7602176);             //    65,536 B
  int*            nbr  = (int*)(ws + 7667712);               //   589,824 B
  int*            deg  = (int*)(ws + 8257536);               //    65,536 B

  prep_kernel<<<256, 256, 0, stream>>>(x, xg, xh, xl, sqv, deg);
  knn_kernel<<<1024, 256, 0, stream>>>(xh, xl, sqv, nbr, deg);
  out_kernel<<<1024, 256, 0, stream>>>(xg, nbr, deg, W0, W1, b, out);
}

// Round 10
// 215.711 us; speedup vs baseline: 1.0072x; 1.0072x over previous
//
#include <hip/hip_runtime.h>

#define NN 16384   // total nodes (4*64*64)
#define CC 48      // channels

typedef __attribute__((ext_vector_type(8))) short bf16x8;
typedef __attribute__((ext_vector_type(4))) float f32x4;

__device__ __forceinline__ unsigned short f2bf(float f) {
  unsigned u = __float_as_uint(f);
  unsigned r = ((u >> 16) & 1u) + 0x7fffu;   // RNE
  return (unsigned short)((u + r) >> 16);
}
__device__ __forceinline__ float bf2f(unsigned short h) {
  return __uint_as_float(((unsigned)h) << 16);
}

// Parallel sorted-insert of key c into ascending q[0..8] (verified R0 form).
// Eight variants (occupancy x2, two-pass u32, u32+payload, __any gate,
// cooperative fuse) have lost to or broken against this plain form. FROZEN.
__device__ __forceinline__ void ins9(double c, double q[9]) {
  double m1 = fmin(q[1], c), m2 = fmin(q[2], c), m3 = fmin(q[3], c),
         m4 = fmin(q[4], c), m5 = fmin(q[5], c), m6 = fmin(q[6], c),
         m7 = fmin(q[7], c), m8 = fmin(q[8], c);
  double n0 = fmin(q[0], c);
  double n1 = fmax(q[0], m1), n2 = fmax(q[1], m2), n3 = fmax(q[2], m3),
         n4 = fmax(q[3], m4), n5 = fmax(q[4], m5), n6 = fmax(q[5], m6),
         n7 = fmax(q[6], m7), n8 = fmax(q[7], m8);
  q[0] = n0; q[1] = n1; q[2] = n2; q[3] = n3; q[4] = n4;
  q[5] = n5; q[6] = n6; q[7] = n7; q[8] = n8;
}

// ---------- kernel 1: prep, 1024 blocks x 16-node slice ----------
// R10: same arithmetic as the verified R7 prep, re-parameterized from 64-node
// to 16-node slices (256 -> 1024 blocks; R7 ran 1 block/CU, pure latency).
// float4 x loads, ushort4 xh/xl stores, deg zeroing, sqv[16383]=+inf.
__global__ __launch_bounds__(256) void prep_kernel(const float* __restrict__ x,
                                                   float* __restrict__ xg,
                                                   unsigned short* __restrict__ xh,
                                                   unsigned short* __restrict__ xl,
                                                   float* __restrict__ sqv,
                                                   int* __restrict__ deg) {
  __shared__ __align__(16) float tile[48][20];   // 16 cols + pad to 20 (80B rows)
  __shared__ float sqcol[16];
  int tid = threadIdx.x;
  int n0    = blockIdx.x * 16;          // first node of this slice
  int batch = n0 >> 12;
  int hw0   = n0 & 4095;                // 16-aligned within the image
  if (tid < 16) deg[n0 + tid] = 0;
  const float4* x4 = (const float4*)x;
  if (tid < 192) {                      // 48 rows x 4 float4 (16 cols)
    int r = tid >> 2, c4 = tid & 3;
    float4 v = x4[(batch * 48 + r) * 1024 + (hw0 >> 2) + c4];
    *(float4*)&tile[r][c4 * 4] = v;
  }
  __syncthreads();
  if (tid < 16) {
    float s = 0.f;
#pragma unroll
    for (int r = 0; r < 48; ++r) { float v = tile[r][tid]; s += v * v; }
    sqcol[tid] = s;
    int node = n0 + tid;
    sqv[node] = (node == NN - 1) ? __builtin_inff() : s;
  }
  __syncthreads();
  float4* xg4 = (float4*)xg;
  if (tid < 208) {                      // 16 nodes x 13 float4
    int col = tid / 13, q = tid - col * 13;
    float4 v;
    if (q < 12) {
      v.x = tile[q * 4 + 0][col]; v.y = tile[q * 4 + 1][col];
      v.z = tile[q * 4 + 2][col]; v.w = tile[q * 4 + 3][col];
    } else {
      v.x = sqcol[col]; v.y = 0.f; v.z = 0.f; v.w = 0.f;
    }
    xg4[(n0 + col) * 13 + q] = v;
  }
  {                                     // 16 nodes x 16 ch-quads = 256 threads
    int col = tid >> 4, cq = tid & 15, ch = cq * 4;
    ushort4 h4, l4;
    if (ch < 48) {
      float v0 = tile[ch + 0][col], v1 = tile[ch + 1][col],
            v2 = tile[ch + 2][col], v3 = tile[ch + 3][col];
      h4.x = f2bf(v0); h4.y = f2bf(v1); h4.z = f2bf(v2); h4.w = f2bf(v3);
      l4.x = f2bf(v0 - bf2f(h4.x)); l4.y = f2bf(v1 - bf2f(h4.y));
      l4.z = f2bf(v2 - bf2f(h4.z)); l4.w = f2bf(v3 - bf2f(h4.w));
    } else {
      h4.x = h4.y = h4.z = h4.w = 0;
      l4.x = l4.y = l4.z = l4.w = 0;
    }
    size_t o = (size_t)(n0 + col) * 64 + ch;
    *(ushort4*)(xh + o) = h4;
    *(ushort4*)(xl + o) = l4;
  }
}

// ---------- kernel 2: MFMA distance + exact f64 top-9, fused final merge ----------
// BYTE-IDENTICAL to the verified R6 kernel (148.5us). FROZEN.
__global__ __launch_bounds__(256, 4) void knn_kernel(const unsigned short* __restrict__ xh,
                                                     const unsigned short* __restrict__ xl,
                                                     const float* __restrict__ sqv,
                                                     int* __restrict__ nbr,
                                                     int* __restrict__ deg) {
  __shared__ unsigned long long fin[4][64][9];   // 18.4 KB, merge staging only
  int tid = threadIdx.x, wv = tid >> 6, lane = tid & 63;
  int qt = blockIdx.x;
  int col = lane & 15, quad = lane >> 4;
  int batch = qt >> 8;
  int cbase = batch * 4096 + wv * 1024;   // this wave's candidate quarter

  // resident B-frags (queries)
  int qnode = qt * 16 + col;
  bf16x8 bh0 = *(const bf16x8*)(xh + (size_t)qnode * 64 + quad * 8);
  bf16x8 bh1 = *(const bf16x8*)(xh + (size_t)qnode * 64 + 32 + quad * 8);
  bf16x8 bl0 = *(const bf16x8*)(xl + (size_t)qnode * 64 + quad * 8);
  bf16x8 bl1 = *(const bf16x8*)(xl + (size_t)qnode * 64 + 32 + quad * 8);

  double q9[9];
#pragma unroll
  for (int k = 0; k < 9; ++k) q9[k] = __builtin_inf();

  // prefetch tile 0: A-frags (candidate node cbase + col) + sq float4
  const unsigned short* pah = xh + ((size_t)(cbase + col) * 64 + quad * 8);
  const unsigned short* pal = xl + ((size_t)(cbase + col) * 64 + quad * 8);
  const float*          psq = sqv + (cbase + quad * 4);
  bf16x8 nh0 = *(const bf16x8*)(pah);
  bf16x8 nh1 = *(const bf16x8*)(pah + 32);
  bf16x8 nl0 = *(const bf16x8*)(pal);
  bf16x8 nl1 = *(const bf16x8*)(pal + 32);
  float4 nsq = *(const float4*)(psq);

  double od = 0.0;   // ordinal base = t*4 (exact integer in f64)
  for (int t = 0; t < 64; ++t) {
    bf16x8 ch0 = nh0, ch1 = nh1, cl0 = nl0, cl1 = nl1;
    float4 csq = nsq;
    int adv = (t < 63) ? 1024 : 0;       // 16 nodes * 64 ch
    pah += adv; pal += adv;
    nh0 = *(const bf16x8*)(pah);
    nh1 = *(const bf16x8*)(pah + 32);
    nl0 = *(const bf16x8*)(pal);
    nl1 = *(const bf16x8*)(pal + 32);
    psq += (t < 63) ? 16 : 0;
    nsq = *(const float4*)(psq);

    f32x4 acc = {0.f, 0.f, 0.f, 0.f};
    acc = __builtin_amdgcn_mfma_f32_16x16x32_bf16(ch0, bh0, acc, 0, 0, 0);  // hi.hi k0-31
    acc = __builtin_amdgcn_mfma_f32_16x16x32_bf16(ch1, bh1, acc, 0, 0, 0);  // hi.hi k32-63
    acc = __builtin_amdgcn_mfma_f32_16x16x32_bf16(ch0, bl0, acc, 0, 0, 0);  // hi.lo
    acc = __builtin_amdgcn_mfma_f32_16x16x32_bf16(ch1, bl1, acc, 0, 0, 0);
    acc = __builtin_amdgcn_mfma_f32_16x16x32_bf16(cl0, bh0, acc, 0, 0, 0);  // lo.hi
    acc = __builtin_amdgcn_mfma_f32_16x16x32_bf16(cl1, bh1, acc, 0, 0, 0);

    float sq4[4] = {csq.x, csq.y, csq.z, csq.w};
#pragma unroll
    for (int reg = 0; reg < 4; ++reg) {
      float d = fmaf(-2.f, acc[reg], sq4[reg]);   // key: sq_j - 2 dot (sq_i dropped)
      unsigned k32 = __float_as_uint(d);
      k32 = ((int)k32 >= 0) ? (k32 | 0x80000000u) : ~k32;   // sortable map
      double key = fma((double)k32, 256.0, od + (double)reg);  // exact 40-bit int
      ins9(key, q9);
    }
    od += 4.0;
  }

  // f64 keys -> exact (k32, o) -> j -> packed u64; stage for in-wave quad merge
  unsigned long long q9u[9];
#pragma unroll
  for (int k = 0; k < 9; ++k) {
    double d  = q9[k];
    double hi = floor(d * 0.00390625);     // d * 2^-8, exact
    double lo = d - hi * 256.0;            // ordinal o, exact
    unsigned k32 = (unsigned)hi;
    int o = (int)lo;
    int j = cbase + (o >> 2) * 16 + quad * 4 + (o & 3);
    q9u[k] = ((unsigned long long)k32 << 14) | (unsigned)j;
    fin[wv][lane][k] = q9u[k];
  }
  __threadfence_block();
  if (lane < 16) {
    // stage 1: merge the wave's 4 quads -> per-wave list for query col=lane
#pragma unroll
    for (int qd = 1; qd < 4; ++qd) {
      const unsigned long long* ob = fin[wv][qd * 16 + lane];
      for (int k = 0; k < 9; ++k) {
        unsigned long long key = ob[k];
        if (key >= q9u[8]) break;          // sorted ascending
        unsigned long long cu = key;
#pragma unroll
        for (int kk = 0; kk < 9; ++kk) {
          bool lt = cu < q9u[kk];
          unsigned long long mn = lt ? cu : q9u[kk];
          cu      = lt ? q9u[kk] : cu;
          q9u[kk] = mn;
        }
      }
    }
    // restage per-wave merged list (only fin[wv][0..15] touched; own quad
    // reads above covered 16..63, other waves never read fin[wv])
#pragma unroll
    for (int k = 0; k < 9; ++k) fin[wv][lane][k] = q9u[k];
  }
  __syncthreads();
  // stage 2: wave 0 merges the 4 per-wave lists -> FINAL top-9; write nbr/deg
  if (wv == 0 && lane < 16) {
#pragma unroll
    for (int ow = 1; ow < 4; ++ow) {
      const unsigned long long* ob = fin[ow][lane];
      for (int k = 0; k < 9; ++k) {
        unsigned long long key = ob[k];
        if (key >= q9u[8]) break;          // sorted ascending
        unsigned long long cu = key;
#pragma unroll
        for (int kk = 0; kk < 9; ++kk) {
          bool lt = cu < q9u[kk];
          unsigned long long mn = lt ? cu : q9u[kk];
          cu      = lt ? q9u[kk] : cu;
          q9u[kk] = mn;
        }
      }
    }
    int i = qt * 16 + lane;
    int outi[9];
#pragma unroll
    for (int k = 0; k < 9; ++k) outi[k] = (int)(q9u[k] & 0x3FFFull);
    // node 16383 sits alone in "batch 4": top_k over one valid entry + (-inf)
    // ties -> neighbors {16383, 0,1,...,7} (lowest-index tie-break).
    if (i == NN - 1) {
      outi[0] = NN - 1;
#pragma unroll
      for (int k = 1; k < 9; ++k) outi[k] = k - 1;
    }
#pragma unroll
    for (int k = 0; k < 9; ++k) {
      nbr[i * 9 + k] = outi[k];
      atomicAdd(&deg[outi[k]], 1);
    }
  }
}

// ---------- kernel 3: tx1 gather + out = relu(xf@W0 + tx1@W1 + b) ----------
// Verified R7 version (1024 blocks x 16 rows, 4 blocks/CU). Unchanged.
__global__ __launch_bounds__(256) void out_kernel(const float* __restrict__ xg,
                                                  const int* __restrict__ nbr,
                                                  const int* __restrict__ deg,
                                                  const float* __restrict__ W0,
                                                  const float* __restrict__ W1,
                                                  const float* __restrict__ bias,
                                                  float* __restrict__ out) {
  __shared__ float w0s[48 * 48], w1s[48 * 48], bsh[48];
  __shared__ __align__(16) float xr[16 * 48];
  __shared__ float tx[16 * 48];
  __shared__ float wd[16][9];
  __shared__ int   jn[16][9];
  __shared__ float din[16];
  int tid = threadIdx.x;
  int r0  = blockIdx.x * 16;

  // weight staging, vectorized: 2304 floats = 576 float4 per matrix
  const float4* W04 = (const float4*)W0;
  const float4* W14 = (const float4*)W1;
  float4* w0s4 = (float4*)w0s;
  float4* w1s4 = (float4*)w1s;
  for (int p = tid; p < 576; p += 256) { w0s4[p] = W04[p]; w1s4[p] = W14[p]; }
  if (tid < 48) bsh[tid] = bias[tid];
  if (tid < 16) {
    int d = deg[r0 + tid];
    din[tid] = d > 0 ? rsqrtf((float)d) : 0.0f;
  }
  const float4* xg4 = (const float4*)xg;
  float4* xr4 = (float4*)xr;
  if (tid < 192) {                      // 16 rows x 12 float4
    int r = tid / 12, q = tid - r * 12;
    xr4[r * 12 + q] = xg4[(r0 + r) * 13 + q];
  }
  if (tid < 144) {                      // 16 rows x 9 neighbors
    int r = tid / 9, k = tid - r * 9;
    int j = nbr[(r0 + r) * 9 + k];
    jn[r][k] = j;
    int d = deg[j];
    wd[r][k] = d > 0 ? rsqrtf((float)d) : 0.0f;
  }
  __syncthreads();

  for (int p = tid; p < 768; p += 256) {   // 16 rows x 48 ch
    int r = p / 48, ch = p - r * 48;
    float s = 0.f;
#pragma unroll
    for (int k = 0; k < 9; ++k) s += wd[r][k] * xg[jn[r][k] * 52 + ch];
    tx[r * 48 + ch] = -din[r] * s;
  }
  __syncthreads();

  for (int p = tid; p < 768; p += 256) {   // 16 rows x 48 outs
    int r = p / 48, o = p - r * 48;
    float acc = bsh[o];
#pragma unroll
    for (int cc = 0; cc < 48; ++cc)
      acc += xr[r * 48 + cc] * w0s[cc * 48 + o] + tx[r * 48 + cc] * w1s[cc * 48 + o];
    out[(r0 + r) * 48 + o] = fmaxf(acc, 0.f);
  }
}

extern "C" void kernel_launch(void* const* d_in, const int* in_sizes, int n_in,
                              void* d_out, int out_size, void* d_ws, size_t ws_size,
                              hipStream_t stream) {
  const float* x  = (const float*)d_in[0];
  const float* W0 = (const float*)d_in[1];
  const float* W1 = (const float*)d_in[2];
  const float* b  = (const float*)d_in[3];
  float* out = (float*)d_out;
  char* ws = (char*)d_ws;
  float*          xg   = (float*)(ws);                       // 3,407,872 B
  unsigned short* xh   = (unsigned short*)(ws + 3407872);    // 2,097,152 B
  unsigned short* xl   = (unsigned short*)(ws + 5505024);    // 2,097,152 B
  float*          sqv  = (float*)(ws + 7602176);             //    65,536 B
  int*            nbr  = (int*)(ws + 7667712);               //   589,824 B
  int*            deg  = (int*)(ws + 8257536);               //    65,536 B

  prep_kernel<<<1024, 256, 0, stream>>>(x, xg, xh, xl, sqv, deg);
  knn_kernel<<<1024, 256, 0, stream>>>(xh, xl, sqv, nbr, deg);
  out_kernel<<<1024, 256, 0, stream>>>(xg, nbr, deg, W0, W1, b, out);
}

// Round 11
// 171.850 us; speedup vs baseline: 1.2642x; 1.2552x over previous
//
#include <hip/hip_runtime.h>

#define NN 16384   // total nodes (4*64*64)
#define CC 48      // channels

typedef __attribute__((ext_vector_type(8))) short bf16x8;
typedef __attribute__((ext_vector_type(4))) float f32x4;

__device__ __forceinline__ unsigned short f2bf(float f) {
  unsigned u = __float_as_uint(f);
  unsigned r = ((u >> 16) & 1u) + 0x7fffu;   // RNE
  return (unsigned short)((u + r) >> 16);
}
__device__ __forceinline__ float bf2f(unsigned short h) {
  return __uint_as_float(((unsigned)h) << 16);
}

// Parallel sorted-insert of key c into ascending q[0..8] (verified R0 form).
// The queue DATATYPE is frozen (8 variants lost); R11 changes per-wave ILP
// only: two independent queues interleave their chains.
__device__ __forceinline__ void ins9(double c, double q[9]) {
  double m1 = fmin(q[1], c), m2 = fmin(q[2], c), m3 = fmin(q[3], c),
         m4 = fmin(q[4], c), m5 = fmin(q[5], c), m6 = fmin(q[6], c),
         m7 = fmin(q[7], c), m8 = fmin(q[8], c);
  double n0 = fmin(q[0], c);
  double n1 = fmax(q[0], m1), n2 = fmax(q[1], m2), n3 = fmax(q[2], m3),
         n4 = fmax(q[3], m4), n5 = fmax(q[4], m5), n6 = fmax(q[5], m6),
         n7 = fmax(q[6], m7), n8 = fmax(q[7], m8);
  q[0] = n0; q[1] = n1; q[2] = n2; q[3] = n3; q[4] = n4;
  q[5] = n5; q[6] = n6; q[7] = n7; q[8] = n8;
}

// 9-way u64 sorted-merge insert used by the staging merges (verified form).
__device__ __forceinline__ void mrg9(const unsigned long long* ob,
                                     unsigned long long q9u[9]) {
  for (int k = 0; k < 9; ++k) {
    unsigned long long key = ob[k];
    if (key >= q9u[8]) break;          // source sorted ascending
    unsigned long long cu = key;
#pragma unroll
    for (int kk = 0; kk < 9; ++kk) {
      bool lt = cu < q9u[kk];
      unsigned long long mn = lt ? cu : q9u[kk];
      cu      = lt ? q9u[kk] : cu;
      q9u[kk] = mn;
    }
  }
}

// ---------- kernel 1: prep, 1024 blocks x 16-node slice (verified R10) ----------
__global__ __launch_bounds__(256) void prep_kernel(const float* __restrict__ x,
                                                   float* __restrict__ xg,
                                                   unsigned short* __restrict__ xh,
                                                   unsigned short* __restrict__ xl,
                                                   float* __restrict__ sqv,
                                                   int* __restrict__ deg) {
  __shared__ __align__(16) float tile[48][20];   // 16 cols + pad to 20 (80B rows)
  __shared__ float sqcol[16];
  int tid = threadIdx.x;
  int n0    = blockIdx.x * 16;          // first node of this slice
  int batch = n0 >> 12;
  int hw0   = n0 & 4095;                // 16-aligned within the image
  if (tid < 16) deg[n0 + tid] = 0;
  const float4* x4 = (const float4*)x;
  if (tid < 192) {                      // 48 rows x 4 float4 (16 cols)
    int r = tid >> 2, c4 = tid & 3;
    float4 v = x4[(batch * 48 + r) * 1024 + (hw0 >> 2) + c4];
    *(float4*)&tile[r][c4 * 4] = v;
  }
  __syncthreads();
  if (tid < 16) {
    float s = 0.f;
#pragma unroll
    for (int r = 0; r < 48; ++r) { float v = tile[r][tid]; s += v * v; }
    sqcol[tid] = s;
    int node = n0 + tid;
    sqv[node] = (node == NN - 1) ? __builtin_inff() : s;
  }
  __syncthreads();
  float4* xg4 = (float4*)xg;
  if (tid < 208) {                      // 16 nodes x 13 float4
    int col = tid / 13, q = tid - col * 13;
    float4 v;
    if (q < 12) {
      v.x = tile[q * 4 + 0][col]; v.y = tile[q * 4 + 1][col];
      v.z = tile[q * 4 + 2][col]; v.w = tile[q * 4 + 3][col];
    } else {
      v.x = sqcol[col]; v.y = 0.f; v.z = 0.f; v.w = 0.f;
    }
    xg4[(n0 + col) * 13 + q] = v;
  }
  {                                     // 16 nodes x 16 ch-quads = 256 threads
    int col = tid >> 4, cq = tid & 15, ch = cq * 4;
    ushort4 h4, l4;
    if (ch < 48) {
      float v0 = tile[ch + 0][col], v1 = tile[ch + 1][col],
            v2 = tile[ch + 2][col], v3 = tile[ch + 3][col];
      h4.x = f2bf(v0); h4.y = f2bf(v1); h4.z = f2bf(v2); h4.w = f2bf(v3);
      l4.x = f2bf(v0 - bf2f(h4.x)); l4.y = f2bf(v1 - bf2f(h4.y));
      l4.z = f2bf(v2 - bf2f(h4.z)); l4.w = f2bf(v3 - bf2f(h4.w));
    } else {
      h4.x = h4.y = h4.z = h4.w = 0;
      l4.x = l4.y = l4.z = l4.w = 0;
    }
    size_t o = (size_t)(n0 + col) * 64 + ch;
    *(ushort4*)(xh + o) = h4;
    *(ushort4*)(xl + o) = l4;
  }
}

// ---------- kernel 2: DUAL-QUERY MFMA distance + exact f64 top-9 ----------
// R11 ILP restructure: block = query tiles (2*bid, 2*bid+1) — always the same
// batch (2b,2b+1 cannot straddle a 256-tile batch boundary) — so ONE candidate
// stream (this wave's quarter, 64 tiles, identical to frozen R6) feeds TWO
// independent per-lane queues. Rationale: R0..R10 showed the kernel is
// stall-bound (VALUBusy 43%, TLP and issue-count changes both neutral); the
// A/B chains (12 MFMA, 8 inserts) have zero mutual dependence, so they fill
// each other's latency slots. A-frag loads/addressing shared (FETCH ~halves);
// wave count halves (per-wave overhead halves). Per-query selection semantics
// byte-equivalent to R6: key = sortable_u32(dist)*256 + ordinal, same decode,
// same 2-stage merge (stage 2 runs wave0 for qtA, wave1 for qtB in parallel).
__global__ __launch_bounds__(256, 4) void knn_kernel(const unsigned short* __restrict__ xh,
                                                     const unsigned short* __restrict__ xl,
                                                     const float* __restrict__ sqv,
                                                     int* __restrict__ nbr,
                                                     int* __restrict__ deg) {
  __shared__ unsigned long long finA[4][64][9];   // 18.4 KB
  __shared__ unsigned long long finB[4][64][9];   // 18.4 KB
  int tid = threadIdx.x, wv = tid >> 6, lane = tid & 63;
  int qtA = blockIdx.x * 2, qtB = qtA + 1;
  int col = lane & 15, quad = lane >> 4;
  int batch = qtA >> 8;                   // == qtB >> 8
  int cbase = batch * 4096 + wv * 1024;   // this wave's candidate quarter

  // resident B-frags (two query tiles)
  int qnA = qtA * 16 + col, qnB = qtB * 16 + col;
  bf16x8 Abh0 = *(const bf16x8*)(xh + (size_t)qnA * 64 + quad * 8);
  bf16x8 Abh1 = *(const bf16x8*)(xh + (size_t)qnA * 64 + 32 + quad * 8);
  bf16x8 Abl0 = *(const bf16x8*)(xl + (size_t)qnA * 64 + quad * 8);
  bf16x8 Abl1 = *(const bf16x8*)(xl + (size_t)qnA * 64 + 32 + quad * 8);
  bf16x8 Bbh0 = *(const bf16x8*)(xh + (size_t)qnB * 64 + quad * 8);
  bf16x8 Bbh1 = *(const bf16x8*)(xh + (size_t)qnB * 64 + 32 + quad * 8);
  bf16x8 Bbl0 = *(const bf16x8*)(xl + (size_t)qnB * 64 + quad * 8);
  bf16x8 Bbl1 = *(const bf16x8*)(xl + (size_t)qnB * 64 + 32 + quad * 8);

  double q9a[9], q9b[9];
#pragma unroll
  for (int k = 0; k < 9; ++k) { q9a[k] = __builtin_inf(); q9b[k] = __builtin_inf(); }

  // prefetch tile 0: shared A-frags (candidate node cbase + col) + sq float4
  const unsigned short* pah = xh + ((size_t)(cbase + col) * 64 + quad * 8);
  const unsigned short* pal = xl + ((size_t)(cbase + col) * 64 + quad * 8);
  const float*          psq = sqv + (cbase + quad * 4);
  bf16x8 nh0 = *(const bf16x8*)(pah);
  bf16x8 nh1 = *(const bf16x8*)(pah + 32);
  bf16x8 nl0 = *(const bf16x8*)(pal);
  bf16x8 nl1 = *(const bf16x8*)(pal + 32);
  float4 nsq = *(const float4*)(psq);

  double od = 0.0;   // ordinal base = t*4 (exact integer in f64), shared
  for (int t = 0; t < 64; ++t) {
    bf16x8 ch0 = nh0, ch1 = nh1, cl0 = nl0, cl1 = nl1;
    float4 csq = nsq;
    int adv = (t < 63) ? 1024 : 0;       // 16 nodes * 64 ch
    pah += adv; pal += adv;
    nh0 = *(const bf16x8*)(pah);
    nh1 = *(const bf16x8*)(pah + 32);
    nl0 = *(const bf16x8*)(pal);
    nl1 = *(const bf16x8*)(pal + 32);
    psq += (t < 63) ? 16 : 0;
    nsq = *(const float4*)(psq);

    f32x4 accA = {0.f, 0.f, 0.f, 0.f};
    f32x4 accB = {0.f, 0.f, 0.f, 0.f};
    accA = __builtin_amdgcn_mfma_f32_16x16x32_bf16(ch0, Abh0, accA, 0, 0, 0);
    accB = __builtin_amdgcn_mfma_f32_16x16x32_bf16(ch0, Bbh0, accB, 0, 0, 0);
    accA = __builtin_amdgcn_mfma_f32_16x16x32_bf16(ch1, Abh1, accA, 0, 0, 0);
    accB = __builtin_amdgcn_mfma_f32_16x16x32_bf16(ch1, Bbh1, accB, 0, 0, 0);
    accA = __builtin_amdgcn_mfma_f32_16x16x32_bf16(ch0, Abl0, accA, 0, 0, 0);
    accB = __builtin_amdgcn_mfma_f32_16x16x32_bf16(ch0, Bbl0, accB, 0, 0, 0);
    accA = __builtin_amdgcn_mfma_f32_16x16x32_bf16(ch1, Abl1, accA, 0, 0, 0);
    accB = __builtin_amdgcn_mfma_f32_16x16x32_bf16(ch1, Bbl1, accB, 0, 0, 0);
    accA = __builtin_amdgcn_mfma_f32_16x16x32_bf16(cl0, Abh0, accA, 0, 0, 0);
    accB = __builtin_amdgcn_mfma_f32_16x16x32_bf16(cl0, Bbh0, accB, 0, 0, 0);
    accA = __builtin_amdgcn_mfma_f32_16x16x32_bf16(cl1, Abh1, accA, 0, 0, 0);
    accB = __builtin_amdgcn_mfma_f32_16x16x32_bf16(cl1, Bbh1, accB, 0, 0, 0);

    float sq4[4] = {csq.x, csq.y, csq.z, csq.w};
#pragma unroll
    for (int reg = 0; reg < 4; ++reg) {
      double ob = od + (double)reg;
      float dA = fmaf(-2.f, accA[reg], sq4[reg]);
      float dB = fmaf(-2.f, accB[reg], sq4[reg]);
      unsigned kA = __float_as_uint(dA);
      unsigned kB = __float_as_uint(dB);
      kA = ((int)kA >= 0) ? (kA | 0x80000000u) : ~kA;
      kB = ((int)kB >= 0) ? (kB | 0x80000000u) : ~kB;
      double keyA = fma((double)kA, 256.0, ob);   // exact 40-bit int
      double keyB = fma((double)kB, 256.0, ob);
      ins9(keyA, q9a);          // two INDEPENDENT chains — scheduler
      ins9(keyB, q9b);          // interleaves them to fill stalls
    }
    od += 4.0;
  }

  // decode both queues -> packed u64; stage for in-wave quad merge
  unsigned long long qua[9], qub[9];
#pragma unroll
  for (int k = 0; k < 9; ++k) {
    double d  = q9a[k];
    double hi = floor(d * 0.00390625);
    double lo = d - hi * 256.0;
    unsigned k32 = (unsigned)hi;
    int o = (int)lo;
    int j = cbase + (o >> 2) * 16 + quad * 4 + (o & 3);
    qua[k] = ((unsigned long long)k32 << 14) | (unsigned)j;
    finA[wv][lane][k] = qua[k];
    d  = q9b[k];
    hi = floor(d * 0.00390625);
    lo = d - hi * 256.0;
    k32 = (unsigned)hi;
    o = (int)lo;
    j = cbase + (o >> 2) * 16 + quad * 4 + (o & 3);
    qub[k] = ((unsigned long long)k32 << 14) | (unsigned)j;
    finB[wv][lane][k] = qub[k];
  }
  __threadfence_block();
  if (lane < 16) {
    // stage 1: merge the wave's 4 quads, per query
#pragma unroll
    for (int qd = 1; qd < 4; ++qd) {
      mrg9(finA[wv][qd * 16 + lane], qua);
      mrg9(finB[wv][qd * 16 + lane], qub);
    }
#pragma unroll
    for (int k = 0; k < 9; ++k) { finA[wv][lane][k] = qua[k]; finB[wv][lane][k] = qub[k]; }
  }
  __syncthreads();
  // stage 2: wave 0 finalizes qtA, wave 1 finalizes qtB (parallel)
  if (wv == 0 && lane < 16) {
#pragma unroll
    for (int ow = 1; ow < 4; ++ow) mrg9(finA[ow][lane], qua);
    int i = qtA * 16 + lane;
    int outi[9];
#pragma unroll
    for (int k = 0; k < 9; ++k) outi[k] = (int)(qua[k] & 0x3FFFull);
    if (i == NN - 1) {          // lone "batch 4" node: neighbors {16383, 0..7}
      outi[0] = NN - 1;
#pragma unroll
      for (int k = 1; k < 9; ++k) outi[k] = k - 1;
    }
#pragma unroll
    for (int k = 0; k < 9; ++k) {
      nbr[i * 9 + k] = outi[k];
      atomicAdd(&deg[outi[k]], 1);
    }
  }
  if (wv == 1 && lane < 16) {
#pragma unroll
    for (int ow = 0; ow < 4; ++ow) {
      if (ow == 1) continue;
      mrg9(finB[ow][lane], qub);
    }
    int i = qtB * 16 + lane;
    int outi[9];
#pragma unroll
    for (int k = 0; k < 9; ++k) outi[k] = (int)(qub[k] & 0x3FFFull);
    if (i == NN - 1) {
      outi[0] = NN - 1;
#pragma unroll
      for (int k = 1; k < 9; ++k) outi[k] = k - 1;
    }
#pragma unroll
    for (int k = 0; k < 9; ++k) {
      nbr[i * 9 + k] = outi[k];
      atomicAdd(&deg[outi[k]], 1);
    }
  }
}

// ---------- kernel 3: tx1 gather + out = relu(xf@W0 + tx1@W1 + b) ----------
// Verified R7/R10 version (1024 blocks x 16 rows). Unchanged.
__global__ __launch_bounds__(256) void out_kernel(const float* __restrict__ xg,
                                                  const int* __restrict__ nbr,
                                                  const int* __restrict__ deg,
                                                  const float* __restrict__ W0,
                                                  const float* __restrict__ W1,
                                                  const float* __restrict__ bias,
                                                  float* __restrict__ out) {
  __shared__ float w0s[48 * 48], w1s[48 * 48], bsh[48];
  __shared__ __align__(16) float xr[16 * 48];
  __shared__ float tx[16 * 48];
  __shared__ float wd[16][9];
  __shared__ int   jn[16][9];
  __shared__ float din[16];
  int tid = threadIdx.x;
  int r0  = blockIdx.x * 16;

  const float4* W04 = (const float4*)W0;
  const float4* W14 = (const float4*)W1;
  float4* w0s4 = (float4*)w0s;
  float4* w1s4 = (float4*)w1s;
  for (int p = tid; p < 576; p += 256) { w0s4[p] = W04[p]; w1s4[p] = W14[p]; }
  if (tid < 48) bsh[tid] = bias[tid];
  if (tid < 16) {
    int d = deg[r0 + tid];
    din[tid] = d > 0 ? rsqrtf((float)d) : 0.0f;
  }
  const float4* xg4 = (const float4*)xg;
  float4* xr4 = (float4*)xr;
  if (tid < 192) {                      // 16 rows x 12 float4
    int r = tid / 12, q = tid - r * 12;
    xr4[r * 12 + q] = xg4[(r0 + r) * 13 + q];
  }
  if (tid < 144) {                      // 16 rows x 9 neighbors
    int r = tid / 9, k = tid - r * 9;
    int j = nbr[(r0 + r) * 9 + k];
    jn[r][k] = j;
    int d = deg[j];
    wd[r][k] = d > 0 ? rsqrtf((float)d) : 0.0f;
  }
  __syncthreads();

  for (int p = tid; p < 768; p += 256) {   // 16 rows x 48 ch
    int r = p / 48, ch = p - r * 48;
    float s = 0.f;
#pragma unroll
    for (int k = 0; k < 9; ++k) s += wd[r][k] * xg[jn[r][k] * 52 + ch];
    tx[r * 48 + ch] = -din[r] * s;
  }
  __syncthreads();

  for (int p = tid; p < 768; p += 256) {   // 16 rows x 48 outs
    int r = p / 48, o = p - r * 48;
    float acc = bsh[o];
#pragma unroll
    for (int cc = 0; cc < 48; ++cc)
      acc += xr[r * 48 + cc] * w0s[cc * 48 + o] + tx[r * 48 + cc] * w1s[cc * 48 + o];
    out[(r0 + r) * 48 + o] = fmaxf(acc, 0.f);
  }
}

extern "C" void kernel_launch(void* const* d_in, const int* in_sizes, int n_in,
                              void* d_out, int out_size, void* d_ws, size_t ws_size,
                              hipStream_t stream) {
  const float* x  = (const float*)d_in[0];
  const float* W0 = (const float*)d_in[1];
  const float* W1 = (const float*)d_in[2];
  const float* b  = (const float*)d_in[3];
  float* out = (float*)d_out;
  char* ws = (char*)d_ws;
  float*          xg   = (float*)(ws);                       // 3,407,872 B
  unsigned short* xh   = (unsigned short*)(ws + 3407872);    // 2,097,152 B
  unsigned short* xl   = (unsigned short*)(ws + 5505024);    // 2,097,152 B
  float*          sqv  = (float*)(ws + 7602176);             //    65,536 B
  int*            nbr  = (int*)(ws + 7667712);               //   589,824 B
  int*            deg  = (int*)(ws + 8257536);               //    65,536 B

  prep_kernel<<<1024, 256, 0, stream>>>(x, xg, xh, xl, sqv, deg);
  knn_kernel<<<512, 256, 0, stream>>>(xh, xl, sqv, nbr, deg);
  out_kernel<<<1024, 256, 0, stream>>>(xg, nbr, deg, W0, W1, b, out);
}

// Round 12
// 171.339 us; speedup vs baseline: 1.2680x; 1.0030x over previous
//
#include <hip/hip_runtime.h>

#define NN 16384   // total nodes (4*64*64)
#define CC 48      // channels

typedef __attribute__((ext_vector_type(8))) short bf16x8;
typedef __attribute__((ext_vector_type(4))) float f32x4;

__device__ __forceinline__ unsigned short f2bf(float f) {
  unsigned u = __float_as_uint(f);
  unsigned r = ((u >> 16) & 1u) + 0x7fffu;   // RNE
  return (unsigned short)((u + r) >> 16);
}
__device__ __forceinline__ float bf2f(unsigned short h) {
  return __uint_as_float(((unsigned)h) << 16);
}

// Parallel sorted-insert of key c into ascending q[0..8] (verified R0 form).
// Queue datatype frozen (8 variants lost). R11 proved the lever is per-wave
// ILP: independent chains fill the DP-pipe stall slots (knn 148->103us).
// R12 widens to 4 chains.
__device__ __forceinline__ void ins9(double c, double q[9]) {
  double m1 = fmin(q[1], c), m2 = fmin(q[2], c), m3 = fmin(q[3], c),
         m4 = fmin(q[4], c), m5 = fmin(q[5], c), m6 = fmin(q[6], c),
         m7 = fmin(q[7], c), m8 = fmin(q[8], c);
  double n0 = fmin(q[0], c);
  double n1 = fmax(q[0], m1), n2 = fmax(q[1], m2), n3 = fmax(q[2], m3),
         n4 = fmax(q[3], m4), n5 = fmax(q[4], m5), n6 = fmax(q[5], m6),
         n7 = fmax(q[6], m7), n8 = fmax(q[7], m8);
  q[0] = n0; q[1] = n1; q[2] = n2; q[3] = n3; q[4] = n4;
  q[5] = n5; q[6] = n6; q[7] = n7; q[8] = n8;
}

// 9-way u64 sorted-merge insert used by the staging merges (verified form).
__device__ __forceinline__ void mrg9(const unsigned long long* ob,
                                     unsigned long long q9u[9]) {
  for (int k = 0; k < 9; ++k) {
    unsigned long long key = ob[k];
    if (key >= q9u[8]) break;          // source sorted ascending
    unsigned long long cu = key;
#pragma unroll
    for (int kk = 0; kk < 9; ++kk) {
      bool lt = cu < q9u[kk];
      unsigned long long mn = lt ? cu : q9u[kk];
      cu      = lt ? q9u[kk] : cu;
      q9u[kk] = mn;
    }
  }
}

// ---------- kernel 1: prep, 1024 blocks x 16-node slice (verified R10) ----------
__global__ __launch_bounds__(256) void prep_kernel(const float* __restrict__ x,
                                                   float* __restrict__ xg,
                                                   unsigned short* __restrict__ xh,
                                                   unsigned short* __restrict__ xl,
                                                   float* __restrict__ sqv,
                                                   int* __restrict__ deg) {
  __shared__ __align__(16) float tile[48][20];   // 16 cols + pad to 20 (80B rows)
  __shared__ float sqcol[16];
  int tid = threadIdx.x;
  int n0    = blockIdx.x * 16;          // first node of this slice
  int batch = n0 >> 12;
  int hw0   = n0 & 4095;                // 16-aligned within the image
  if (tid < 16) deg[n0 + tid] = 0;
  const float4* x4 = (const float4*)x;
  if (tid < 192) {                      // 48 rows x 4 float4 (16 cols)
    int r = tid >> 2, c4 = tid & 3;
    float4 v = x4[(batch * 48 + r) * 1024 + (hw0 >> 2) + c4];
    *(float4*)&tile[r][c4 * 4] = v;
  }
  __syncthreads();
  if (tid < 16) {
    float s = 0.f;
#pragma unroll
    for (int r = 0; r < 48; ++r) { float v = tile[r][tid]; s += v * v; }
    sqcol[tid] = s;
    int node = n0 + tid;
    sqv[node] = (node == NN - 1) ? __builtin_inff() : s;
  }
  __syncthreads();
  float4* xg4 = (float4*)xg;
  if (tid < 208) {                      // 16 nodes x 13 float4
    int col = tid / 13, q = tid - col * 13;
    float4 v;
    if (q < 12) {
      v.x = tile[q * 4 + 0][col]; v.y = tile[q * 4 + 1][col];
      v.z = tile[q * 4 + 2][col]; v.w = tile[q * 4 + 3][col];
    } else {
      v.x = sqcol[col]; v.y = 0.f; v.z = 0.f; v.w = 0.f;
    }
    xg4[(n0 + col) * 13 + q] = v;
  }
  {                                     // 16 nodes x 16 ch-quads = 256 threads
    int col = tid >> 4, cq = tid & 15, ch = cq * 4;
    ushort4 h4, l4;
    if (ch < 48) {
      float v0 = tile[ch + 0][col], v1 = tile[ch + 1][col],
            v2 = tile[ch + 2][col], v3 = tile[ch + 3][col];
      h4.x = f2bf(v0); h4.y = f2bf(v1); h4.z = f2bf(v2); h4.w = f2bf(v3);
      l4.x = f2bf(v0 - bf2f(h4.x)); l4.y = f2bf(v1 - bf2f(h4.y));
      l4.z = f2bf(v2 - bf2f(h4.z)); l4.w = f2bf(v3 - bf2f(h4.w));
    } else {
      h4.x = h4.y = h4.z = h4.w = 0;
      l4.x = l4.y = l4.z = l4.w = 0;
    }
    size_t o = (size_t)(n0 + col) * 64 + ch;
    *(ushort4*)(xh + o) = h4;
    *(ushort4*)(xl + o) = l4;
  }
}

// ---------- kernel 2: QUAD-QUERY MFMA distance + exact f64 top-9 ----------
// R12: block = query tiles 4*bid..4*bid+3 (never straddles a batch; 256%4==0).
// One candidate stream (this wave's quarter, 64 tiles — frozen R6 pattern)
// feeds FOUR independent per-lane queues: 24 MFMA + 16 inserts per tile in 4
// mutually independent chains (R11 measured the chain-stall as the bottleneck;
// 2 chains: 148->103us). Wave count halves again (per-wave fixed overhead),
// candidate loads amortized 4x. launch_bounds(256,2) caps VGPR at 256 (est
// ~200 live: 64 B-frag + 72 queue + 32 cand + accs/temps) — spill would show
// as WRITE_SIZE inflation (R1 signature). Per-query selection semantics are
// byte-equivalent to frozen R6 (same key, same decode, same 2-stage merge;
// stage 2: wave w finalizes query w, 4-way parallel).
__global__ __launch_bounds__(256, 2) void knn_kernel(const unsigned short* __restrict__ xh,
                                                     const unsigned short* __restrict__ xl,
                                                     const float* __restrict__ sqv,
                                                     int* __restrict__ nbr,
                                                     int* __restrict__ deg) {
  __shared__ unsigned long long fin[4][4][64][9];   // [query][wave][lane][k] 73.7KB
  int tid = threadIdx.x, wv = tid >> 6, lane = tid & 63;
  int qt0 = blockIdx.x * 4;
  int col = lane & 15, quad = lane >> 4;
  int batch = qt0 >> 8;
  int cbase = batch * 4096 + wv * 1024;   // this wave's candidate quarter

  // resident B-frags: 4 query tiles (static indexing via full unroll)
  bf16x8 bh0[4], bh1[4], bl0[4], bl1[4];
#pragma unroll
  for (int q = 0; q < 4; ++q) {
    int qn = (qt0 + q) * 16 + col;
    bh0[q] = *(const bf16x8*)(xh + (size_t)qn * 64 + quad * 8);
    bh1[q] = *(const bf16x8*)(xh + (size_t)qn * 64 + 32 + quad * 8);
    bl0[q] = *(const bf16x8*)(xl + (size_t)qn * 64 + quad * 8);
    bl1[q] = *(const bf16x8*)(xl + (size_t)qn * 64 + 32 + quad * 8);
  }

  double q9[4][9];
#pragma unroll
  for (int q = 0; q < 4; ++q)
#pragma unroll
    for (int k = 0; k < 9; ++k) q9[q][k] = __builtin_inf();

  // prefetch tile 0: shared A-frags (candidate node cbase + col) + sq float4
  const unsigned short* pah = xh + ((size_t)(cbase + col) * 64 + quad * 8);
  const unsigned short* pal = xl + ((size_t)(cbase + col) * 64 + quad * 8);
  const float*          psq = sqv + (cbase + quad * 4);
  bf16x8 nh0 = *(const bf16x8*)(pah);
  bf16x8 nh1 = *(const bf16x8*)(pah + 32);
  bf16x8 nl0 = *(const bf16x8*)(pal);
  bf16x8 nl1 = *(const bf16x8*)(pal + 32);
  float4 nsq = *(const float4*)(psq);

  double od = 0.0;   // ordinal base = t*4 (exact integer in f64), shared
  for (int t = 0; t < 64; ++t) {
    bf16x8 ch0 = nh0, ch1 = nh1, cl0 = nl0, cl1 = nl1;
    float4 csq = nsq;
    int adv = (t < 63) ? 1024 : 0;       // 16 nodes * 64 ch
    pah += adv; pal += adv;
    nh0 = *(const bf16x8*)(pah);
    nh1 = *(const bf16x8*)(pah + 32);
    nl0 = *(const bf16x8*)(pal);
    nl1 = *(const bf16x8*)(pal + 32);
    psq += (t < 63) ? 16 : 0;
    nsq = *(const float4*)(psq);

    f32x4 acc[4];
#pragma unroll
    for (int q = 0; q < 4; ++q) acc[q] = (f32x4){0.f, 0.f, 0.f, 0.f};
#pragma unroll
    for (int q = 0; q < 4; ++q)
      acc[q] = __builtin_amdgcn_mfma_f32_16x16x32_bf16(ch0, bh0[q], acc[q], 0, 0, 0);
#pragma unroll
    for (int q = 0; q < 4; ++q)
      acc[q] = __builtin_amdgcn_mfma_f32_16x16x32_bf16(ch1, bh1[q], acc[q], 0, 0, 0);
#pragma unroll
    for (int q = 0; q < 4; ++q)
      acc[q] = __builtin_amdgcn_mfma_f32_16x16x32_bf16(ch0, bl0[q], acc[q], 0, 0, 0);
#pragma unroll
    for (int q = 0; q < 4; ++q)
      acc[q] = __builtin_amdgcn_mfma_f32_16x16x32_bf16(ch1, bl1[q], acc[q], 0, 0, 0);
#pragma unroll
    for (int q = 0; q < 4; ++q)
      acc[q] = __builtin_amdgcn_mfma_f32_16x16x32_bf16(cl0, bh0[q], acc[q], 0, 0, 0);
#pragma unroll
    for (int q = 0; q < 4; ++q)
      acc[q] = __builtin_amdgcn_mfma_f32_16x16x32_bf16(cl1, bh1[q], acc[q], 0, 0, 0);

    float sq4[4] = {csq.x, csq.y, csq.z, csq.w};
#pragma unroll
    for (int reg = 0; reg < 4; ++reg) {
      double ob = od + (double)reg;
#pragma unroll
      for (int q = 0; q < 4; ++q) {       // 4 independent insert chains
        float d = fmaf(-2.f, acc[q][reg], sq4[reg]);
        unsigned k32 = __float_as_uint(d);
        k32 = ((int)k32 >= 0) ? (k32 | 0x80000000u) : ~k32;   // sortable map
        double key = fma((double)k32, 256.0, ob);   // exact 40-bit int
        ins9(key, q9[q]);
      }
    }
    od += 4.0;
  }

  // decode each queue -> packed u64 -> LDS (frees the f64 queue regs per q)
#pragma unroll
  for (int q = 0; q < 4; ++q) {
#pragma unroll
    for (int k = 0; k < 9; ++k) {
      double d  = q9[q][k];
      double hi = floor(d * 0.00390625);     // d * 2^-8, exact
      double lo = d - hi * 256.0;            // ordinal o, exact
      unsigned k32 = (unsigned)hi;
      int o = (int)lo;
      int j = cbase + (o >> 2) * 16 + quad * 4 + (o & 3);
      fin[q][wv][lane][k] = ((unsigned long long)k32 << 14) | (unsigned)j;
    }
  }
  __threadfence_block();
  if (lane < 16) {
    // stage 1: per query, merge this wave's 4 quads (reload own from LDS to
    // avoid holding 4x9 u64 live across all four merges)
#pragma unroll
    for (int q = 0; q < 4; ++q) {
      unsigned long long qu[9];
#pragma unroll
      for (int k = 0; k < 9; ++k) qu[k] = fin[q][wv][lane][k];
#pragma unroll
      for (int qd = 1; qd < 4; ++qd) mrg9(fin[q][wv][qd * 16 + lane], qu);
#pragma unroll
      for (int k = 0; k < 9; ++k) fin[q][wv][lane][k] = qu[k];
    }
  }
  __syncthreads();
  // stage 2: wave w finalizes query w (4-way parallel); write nbr/deg
  if (lane < 16) {
    unsigned long long qu[9];
#pragma unroll
    for (int k = 0; k < 9; ++k) qu[k] = fin[wv][wv][lane][k];
#pragma unroll
    for (int ow = 0; ow < 4; ++ow) {
      if (ow == wv) continue;
      mrg9(fin[wv][ow][lane], qu);
    }
    int i = (qt0 + wv) * 16 + lane;
    int outi[9];
#pragma unroll
    for (int k = 0; k < 9; ++k) outi[k] = (int)(qu[k] & 0x3FFFull);
    // node 16383 sits alone in "batch 4": neighbors {16383, 0..7}
    if (i == NN - 1) {
      outi[0] = NN - 1;
#pragma unroll
      for (int k = 1; k < 9; ++k) outi[k] = k - 1;
    }
#pragma unroll
    for (int k = 0; k < 9; ++k) {
      nbr[i * 9 + k] = outi[k];
      atomicAdd(&deg[outi[k]], 1);
    }
  }
}

// ---------- kernel 3: tx1 gather + out = relu(xf@W0 + tx1@W1 + b) ----------
// Verified R7/R10 version (1024 blocks x 16 rows). Unchanged.
__global__ __launch_bounds__(256) void out_kernel(const float* __restrict__ xg,
                                                  const int* __restrict__ nbr,
                                                  const int* __restrict__ deg,
                                                  const float* __restrict__ W0,
                                                  const float* __restrict__ W1,
                                                  const float* __restrict__ bias,
                                                  float* __restrict__ out) {
  __shared__ float w0s[48 * 48], w1s[48 * 48], bsh[48];
  __shared__ __align__(16) float xr[16 * 48];
  __shared__ float tx[16 * 48];
  __shared__ float wd[16][9];
  __shared__ int   jn[16][9];
  __shared__ float din[16];
  int tid = threadIdx.x;
  int r0  = blockIdx.x * 16;

  const float4* W04 = (const float4*)W0;
  const float4* W14 = (const float4*)W1;
  float4* w0s4 = (float4*)w0s;
  float4* w1s4 = (float4*)w1s;
  for (int p = tid; p < 576; p += 256) { w0s4[p] = W04[p]; w1s4[p] = W14[p]; }
  if (tid < 48) bsh[tid] = bias[tid];
  if (tid < 16) {
    int d = deg[r0 + tid];
    din[tid] = d > 0 ? rsqrtf((float)d) : 0.0f;
  }
  const float4* xg4 = (const float4*)xg;
  float4* xr4 = (float4*)xr;
  if (tid < 192) {                      // 16 rows x 12 float4
    int r = tid / 12, q = tid - r * 12;
    xr4[r * 12 + q] = xg4[(r0 + r) * 13 + q];
  }
  if (tid < 144) {                      // 16 rows x 9 neighbors
    int r = tid / 9, k = tid - r * 9;
    int j = nbr[(r0 + r) * 9 + k];
    jn[r][k] = j;
    int d = deg[j];
    wd[r][k] = d > 0 ? rsqrtf((float)d) : 0.0f;
  }
  __syncthreads();

  for (int p = tid; p < 768; p += 256) {   // 16 rows x 48 ch
    int r = p / 48, ch = p - r * 48;
    float s = 0.f;
#pragma unroll
    for (int k = 0; k < 9; ++k) s += wd[r][k] * xg[jn[r][k] * 52 + ch];
    tx[r * 48 + ch] = -din[r] * s;
  }
  __syncthreads();

  for (int p = tid; p < 768; p += 256) {   // 16 rows x 48 outs
    int r = p / 48, o = p - r * 48;
    float acc = bsh[o];
#pragma unroll
    for (int cc = 0; cc < 48; ++cc)
      acc += xr[r * 48 + cc] * w0s[cc * 48 + o] + tx[r * 48 + cc] * w1s[cc * 48 + o];
    out[(r0 + r) * 48 + o] = fmaxf(acc, 0.f);
  }
}

extern "C" void kernel_launch(void* const* d_in, const int* in_sizes, int n_in,
                              void* d_out, int out_size, void* d_ws, size_t ws_size,
                              hipStream_t stream) {
  const float* x  = (const float*)d_in[0];
  const float* W0 = (const float*)d_in[1];
  const float* W1 = (const float*)d_in[2];
  const float* b  = (const float*)d_in[3];
  float* out = (float*)d_out;
  char* ws = (char*)d_ws;
  float*          xg   = (float*)(ws);                       // 3,407,872 B
  unsigned short* xh   = (unsigned short*)(ws + 3407872);    // 2,097,152 B
  unsigned short* xl   = (unsigned short*)(ws + 5505024);    // 2,097,152 B
  float*          sqv  = (float*)(ws + 7602176);             //    65,536 B
  int*            nbr  = (int*)(ws + 7667712);               //   589,824 B
  int*            deg  = (int*)(ws + 8257536);               //    65,536 B

  prep_kernel<<<1024, 256, 0, stream>>>(x, xg, xh, xl, sqv, deg);
  knn_kernel<<<256, 256, 0, stream>>>(xh, xl, sqv, nbr, deg);
  out_kernel<<<1024, 256, 0, stream>>>(xg, nbr, deg, W0, W1, b, out);
}